// Round 6
// baseline (215.403 us; speedup 1.0000x reference)
//
#include <hip/hip_runtime.h>
#include <math.h>

#define C_DIM 4
#define T_DIM 4096
#define D_DIM 1024
#define E_DIM 16
#define CAP   320
#define CT    (C_DIM * T_DIM)               // 16384 tokens
#define OUT_ONE ((size_t)CT * E_DIM * CAP)  // 83,886,080 elements per big output
#define N4      ((2 * OUT_ONE) / 4)         // 41,943,040 float4 to zero

#define ROUTER_BLOCKS 1024                  // 16 tokens per block (4 per wave)
#define FILL_BLOCKS   4096

// compile-time 6-bit bit-reverse (flatten permutation for the butterfly reduce)
__host__ __device__ constexpr int bitrev6(int i) {
    return ((i & 1) << 5) | ((i & 2) << 3) | ((i & 4) << 1)
         | ((i & 8) >> 1) | ((i & 16) >> 3) | ((i & 32) >> 5);
}

// ws layout (bytes):
//   0      : auxpart f32[64]   (per-(c,e) softmax prob sums) - zeroed each call
//   256    : counts  i32[64]   (per-(c,e) argmax histogram)  - zeroed each call
//   512    : gate    f32[CT]
//   66048  : index   i32[CT]

// ---------------------------------------------------------------------------
// Router: 1024 blocks x 16 tokens (4/wave). Butterfly transpose-reduce gives
// lane l the complete logit for (tk=l>>4, e=l&15); softmax/argmax/aux are then
// fully wave-parallel (no lane-0 serial epilogue, 16 parallel LDS atomics).
// ---------------------------------------------------------------------------
__global__ __launch_bounds__(256) void router_kernel(
    const float* __restrict__ in, const float* __restrict__ w,
    const float* __restrict__ noise, float* __restrict__ gate,
    int* __restrict__ index, float* __restrict__ auxpart,
    int* __restrict__ counts)
{
    __shared__ float psum[E_DIM];
    __shared__ int   hcnt[E_DIM];
    const int tid = threadIdx.x;
    if (tid < E_DIM) { psum[tid] = 0.0f; hcnt[tid] = 0; }
    __syncthreads();

    const int wave = tid >> 6;
    const int lane = tid & 63;
    const int g0   = blockIdx.x * 16 + wave * 4;   // 4 tokens per wave

    float val[64];
    #pragma unroll
    for (int i = 0; i < 64; ++i) val[i] = 0.0f;

    #pragma unroll
    for (int r = 0; r < 4; ++r) {
        const int d0 = r * 256 + lane * 4;
        float4 x[4];
        #pragma unroll
        for (int tk = 0; tk < 4; ++tk) {
            const float4 a = *(const float4*)(in    + (size_t)(g0 + tk) * D_DIM + d0);
            const float4 n = *(const float4*)(noise + (size_t)(g0 + tk) * D_DIM + d0);
            x[tk] = make_float4(a.x * n.x, a.y * n.y, a.z * n.z, a.w * n.w);
        }
        #pragma unroll
        for (int e = 0; e < 16; ++e) {
            const float4 wv = *(const float4*)(w + e * D_DIM + d0);
            #pragma unroll
            for (int tk = 0; tk < 4; ++tk) {
                val[bitrev6(tk * 16 + e)] += x[tk].x * wv.x + x[tk].y * wv.y
                                           + x[tk].z * wv.z + x[tk].w * wv.w;
            }
        }
    }

    // Butterfly transpose-reduce: 63 shuffles; lane l ends with the full dot
    // for flattened idx l (bitrev6 flatten compensates the halving order).
    #pragma unroll
    for (int m = 0; m < 6; ++m) {
        const int half = 32 >> m;
        const int bit  = (lane >> m) & 1;
        #pragma unroll
        for (int j = 0; j < half; ++j) {
            const float send = bit ? val[j] : val[j + half];
            const float recv = __shfl_xor(send, 1 << m, 64);
            val[j] = (bit ? val[j + half] : val[j]) + recv;
        }
    }

    const int tk = lane >> 4;
    const int e  = lane & 15;
    const float logit = val[0];
    const int g = g0 + tk;

    // group (16-lane) max with first-index tie-break
    float mv = logit; int am = e;
    #pragma unroll
    for (int msk = 1; msk <= 8; msk <<= 1) {
        const float ov = __shfl_xor(mv, msk, 64);
        const int   oe = __shfl_xor(am, msk, 64);
        if (ov > mv || (ov == mv && oe < am)) { mv = ov; am = oe; }
    }

    const float p = __expf(logit - mv);
    float s = p;
    #pragma unroll
    for (int msk = 1; msk <= 8; msk <<= 1)
        s += __shfl_xor(s, msk, 64);

    const float inv = 1.0f / s;
    if (e == am) {                       // exactly one lane per token
        gate[g]  = inv;                  // probs[argmax] = exp(0)/s
        index[g] = am;
        atomicAdd(&hcnt[am], 1);
    }

    // sum normalized probs over this wave's 4 tokens (lanes differing in bits 4,5)
    float pn = p * inv;
    pn += __shfl_xor(pn, 16, 64);
    pn += __shfl_xor(pn, 32, 64);
    if (lane < 16)
        atomicAdd(&psum[e], pn * 0.25f * 4.0f);   // 4 lanes (tk groups) hold same value? no:
    // NOTE: after xor-16/32, ALL lanes hold the per-e total; only lanes 0..15 add once.

    __syncthreads();
    if (tid < 16) {
        const int c = blockIdx.x >> 8;   // 256 blocks per c
        atomicAdd(&auxpart[c * 16 + tid], psum[tid]);
        atomicAdd(&counts [c * 16 + tid], hcnt[tid]);
    }
}

// ---------------------------------------------------------------------------
// Dedicated low-VGPR zero-fill (rocclr-style grid-stride float4).
// ---------------------------------------------------------------------------
__global__ __launch_bounds__(256) void fill_kernel(float4* __restrict__ out4)
{
    const size_t stride = (size_t)FILL_BLOCKS * 256;
    const float4 z = make_float4(0.f, 0.f, 0.f, 0.f);
    #pragma unroll 4
    for (size_t i = (size_t)blockIdx.x * 256 + threadIdx.x; i < N4; i += stride)
        out4[i] = z;
}

// ---------------------------------------------------------------------------
// Finalize: <=64 nonzeros (torch scatter semantics: only tokens tp<16, e=0
// slice). Rank within expert 0 computed from the first 16 indices (<=16<CAP).
// ---------------------------------------------------------------------------
__global__ __launch_bounds__(64) void finalize_kernel(
    const float* __restrict__ gate, const int* __restrict__ index,
    const int* __restrict__ counts, const float* __restrict__ auxpart,
    float* __restrict__ out)
{
    const int id = threadIdx.x;          // 0..63
    const int c  = id >> 4;
    const int tp = id & 15;
    const int cnt = counts[id];

    float term = ((float)cnt * (1.0f / T_DIM)) * (auxpart[id] * (1.0f / T_DIM));

    if (cnt > 0) {                        // expert value tp appears as an argmax
        const int g     = c * T_DIM + tp;
        const int myidx = index[g];
        int s = 0;
        if (myidx == 0) {                 // 1-based rank within expert 0 among tokens 0..tp
            int r = 0;
            for (int t = 0; t <= tp; ++t)
                r += (index[c * T_DIM + t] == 0);
            s = r;
        }
        const size_t off = ((size_t)g * E_DIM + 0) * CAP + (size_t)s;
        out[off]            = 1.0f;       // dispatch
        out[OUT_ONE + off]  = gate[g];    // combine
    }

    #pragma unroll
    for (int off = 32; off; off >>= 1)
        term += __shfl_down(term, off, 64);
    if (id == 0)
        out[2 * OUT_ONE] = 16.0f * term;  // aux_loss = E * sum(density1*proxy)
}

extern "C" void kernel_launch(void* const* d_in, const int* in_sizes, int n_in,
                              void* d_out, int out_size, void* d_ws, size_t ws_size,
                              hipStream_t stream) {
    const float* in    = (const float*)d_in[0];
    const float* w     = (const float*)d_in[1];
    const float* noise = (const float*)d_in[2];
    float* out = (float*)d_out;

    char* ws = (char*)d_ws;
    float* auxpart = (float*)(ws);
    int*   counts  = (int*)(ws + 256);
    float* gate    = (float*)(ws + 512);
    int*   index   = (int*)(ws + 512 + 65536);

    (void)hipMemsetAsync(ws, 0, 512, stream);

    router_kernel<<<dim3(ROUTER_BLOCKS), dim3(256), 0, stream>>>(
        in, w, noise, gate, index, auxpart, counts);
    fill_kernel<<<dim3(FILL_BLOCKS), dim3(256), 0, stream>>>((float4*)out);
    finalize_kernel<<<dim3(1), dim3(64), 0, stream>>>(gate, index, counts, auxpart, out);
}

// Round 7
// 181.890 us; speedup vs baseline: 1.1842x; 1.1842x over previous
//
#include <hip/hip_runtime.h>
#include <math.h>

#define C_DIM 4
#define T_DIM 4096
#define D_DIM 1024
#define E_DIM 16
#define CAP   320
#define CT    (C_DIM * T_DIM)               // 16384 tokens
#define OUT_ONE ((size_t)CT * E_DIM * CAP)  // 83,886,080 elements per big output

#define NBLOCKS 1024                         // 16 tokens per block (4 per wave)
#define N4      ((2 * OUT_ONE) / 4)          // 41,943,040 float4 to zero
#define F4_PER_BLOCK (N4 / NBLOCKS)          // 40960 float4 per block (640KB)

// ws layout (bytes):
//   0      : auxpart f32[64]   (per-(c,e) softmax prob sums) - zeroed each call
//   256    : counts  i32[64]   (per-(c,e) argmax histogram)  - zeroed each call
//   512    : gate    f32[CT]
//   66048  : index   i32[CT]

// ---------------------------------------------------------------------------
// Router phase (R5-proven): 16 tokens per block, 4 per wave; 64-lane split-K
// dots, shuffle reduce, lane-0 softmax/argmax; LDS psum/hist -> global atomics.
// ---------------------------------------------------------------------------
__device__ __forceinline__ void do_router(
    const float* __restrict__ in, const float* __restrict__ w,
    const float* __restrict__ noise, float* __restrict__ gate,
    int* __restrict__ index, float* __restrict__ auxpart,
    int* __restrict__ counts, float* psum, int* hcnt)
{
    const int tid = threadIdx.x;
    if (tid < E_DIM) { psum[tid] = 0.0f; hcnt[tid] = 0; }
    __syncthreads();

    const int wave = tid >> 6;
    const int lane = tid & 63;
    const int g0   = blockIdx.x * 16 + wave * 4;   // 4 tokens per wave

    float acc[4][16];
    #pragma unroll
    for (int tk = 0; tk < 4; ++tk)
        #pragma unroll
        for (int e = 0; e < 16; ++e)
            acc[tk][e] = 0.0f;

    #pragma unroll
    for (int r = 0; r < 4; ++r) {
        const int d0 = r * 256 + lane * 4;
        float4 x[4];
        #pragma unroll
        for (int tk = 0; tk < 4; ++tk) {
            const float4 a = *(const float4*)(in    + (size_t)(g0 + tk) * D_DIM + d0);
            const float4 n = *(const float4*)(noise + (size_t)(g0 + tk) * D_DIM + d0);
            x[tk] = make_float4(a.x * n.x, a.y * n.y, a.z * n.z, a.w * n.w);
        }
        #pragma unroll
        for (int e = 0; e < 16; ++e) {
            const float4 wv = *(const float4*)(w + e * D_DIM + d0);
            #pragma unroll
            for (int tk = 0; tk < 4; ++tk) {
                acc[tk][e] += x[tk].x * wv.x + x[tk].y * wv.y
                            + x[tk].z * wv.z + x[tk].w * wv.w;
            }
        }
    }

    #pragma unroll
    for (int tk = 0; tk < 4; ++tk)
        #pragma unroll
        for (int e = 0; e < 16; ++e)
            #pragma unroll
            for (int off = 32; off; off >>= 1)
                acc[tk][e] += __shfl_down(acc[tk][e], off, 64);

    if (lane == 0) {
        #pragma unroll
        for (int tk = 0; tk < 4; ++tk) {
            const int g = g0 + tk;
            float m = -1e30f; int am = 0;
            #pragma unroll
            for (int e = 0; e < 16; ++e)
                if (acc[tk][e] > m) { m = acc[tk][e]; am = e; }
            float p[16]; float s = 0.0f;
            #pragma unroll
            for (int e = 0; e < 16; ++e) { p[e] = __expf(acc[tk][e] - m); s += p[e]; }
            const float inv = 1.0f / s;
            gate[g]  = inv;          // probs[argmax] = exp(0)/s
            index[g] = am;
            atomicAdd(&hcnt[am], 1);
            #pragma unroll
            for (int e = 0; e < 16; ++e)
                atomicAdd(&psum[e], p[e] * inv);
        }
    }
    __syncthreads();
    if (tid < 16) {
        const int c = blockIdx.x >> 8;    // 256 blocks per c
        atomicAdd(&auxpart[c * 16 + tid], psum[tid]);
        atomicAdd(&counts [c * 16 + tid], hcnt[tid]);
    }
}

__device__ __forceinline__ void do_fill(float4* __restrict__ out4)
{
    const float4 z = make_float4(0.f, 0.f, 0.f, 0.f);
    float4* dst = out4 + (size_t)blockIdx.x * F4_PER_BLOCK;
    #pragma unroll 4
    for (int i = threadIdx.x; i < F4_PER_BLOCK; i += 256)
        dst[i] = z;
}

// ---------------------------------------------------------------------------
// Fused kernel with PARITY STAGGER: even blocks route then fill, odd blocks
// fill then route. At any instant ~half the resident waves are streaming
// writes while the other half streams reads -> read time hides under writes.
// ---------------------------------------------------------------------------
__global__ __launch_bounds__(256) void fused_router_fill_kernel(
    const float* __restrict__ in, const float* __restrict__ w,
    const float* __restrict__ noise, float* __restrict__ gate,
    int* __restrict__ index, float* __restrict__ auxpart,
    int* __restrict__ counts, float4* __restrict__ out4)
{
    __shared__ float psum[E_DIM];
    __shared__ int   hcnt[E_DIM];

    if (blockIdx.x & 1) {
        do_fill(out4);
        do_router(in, w, noise, gate, index, auxpart, counts, psum, hcnt);
    } else {
        do_router(in, w, noise, gate, index, auxpart, counts, psum, hcnt);
        do_fill(out4);
    }
}

// ---------------------------------------------------------------------------
// Finalize: <=64 nonzeros (torch scatter semantics: only tokens tp<16, e=0
// slice). Rank within expert 0 computed from the first 16 indices (<=16<CAP).
// ---------------------------------------------------------------------------
__global__ __launch_bounds__(64) void finalize_kernel(
    const float* __restrict__ gate, const int* __restrict__ index,
    const int* __restrict__ counts, const float* __restrict__ auxpart,
    float* __restrict__ out)
{
    const int id = threadIdx.x;          // 0..63
    const int c  = id >> 4;
    const int tp = id & 15;
    const int cnt = counts[id];

    float term = ((float)cnt * (1.0f / T_DIM)) * (auxpart[id] * (1.0f / T_DIM));

    if (cnt > 0) {                        // expert value tp appears as an argmax
        const int g     = c * T_DIM + tp;
        const int myidx = index[g];
        int s = 0;
        if (myidx == 0) {                 // 1-based rank within expert 0 among tokens 0..tp
            int r = 0;
            for (int t = 0; t <= tp; ++t)
                r += (index[c * T_DIM + t] == 0);
            s = r;
        }
        const size_t off = ((size_t)g * E_DIM + 0) * CAP + (size_t)s;
        out[off]            = 1.0f;       // dispatch
        out[OUT_ONE + off]  = gate[g];    // combine
    }

    #pragma unroll
    for (int off = 32; off; off >>= 1)
        term += __shfl_down(term, off, 64);
    if (id == 0)
        out[2 * OUT_ONE] = 16.0f * term;  // aux_loss = E * sum(density1*proxy)
}

extern "C" void kernel_launch(void* const* d_in, const int* in_sizes, int n_in,
                              void* d_out, int out_size, void* d_ws, size_t ws_size,
                              hipStream_t stream) {
    const float* in    = (const float*)d_in[0];
    const float* w     = (const float*)d_in[1];
    const float* noise = (const float*)d_in[2];
    float* out = (float*)d_out;

    char* ws = (char*)d_ws;
    float* auxpart = (float*)(ws);
    int*   counts  = (int*)(ws + 256);
    float* gate    = (float*)(ws + 512);
    int*   index   = (int*)(ws + 512 + 65536);

    (void)hipMemsetAsync(ws, 0, 512, stream);

    fused_router_fill_kernel<<<dim3(NBLOCKS), dim3(256), 0, stream>>>(
        in, w, noise, gate, index, auxpart, counts, (float4*)out);
    finalize_kernel<<<dim3(1), dim3(64), 0, stream>>>(gate, index, counts, auxpart, out);
}

// Round 8
// 170.811 us; speedup vs baseline: 1.2611x; 1.0649x over previous
//
#include <hip/hip_runtime.h>
#include <math.h>

#define C_DIM 4
#define T_DIM 4096
#define D_DIM 1024
#define E_DIM 16
#define CAP   320
#define CT    (C_DIM * T_DIM)               // 16384 tokens
#define OUT_ONE ((size_t)CT * E_DIM * CAP)  // 83,886,080 elements per big output

#define NBLOCKS 1024                         // 16 tokens per block (4 per wave)
#define N4      ((2 * OUT_ONE) / 4)          // 41,943,040 float4 to zero
#define F4_PER_BLOCK (N4 / NBLOCKS)          // 40960 float4 per block (640KB)

// compile-time 6-bit bit-reverse (flatten permutation for the butterfly reduce)
__host__ __device__ constexpr int bitrev6(int i) {
    return ((i & 1) << 5) | ((i & 2) << 3) | ((i & 4) << 1)
         | ((i & 8) >> 1) | ((i & 16) >> 3) | ((i & 32) >> 5);
}

// ws layout (bytes):
//   0      : auxpart f32[64]   (per-(c,e) softmax prob sums) - zeroed each call
//   256    : counts  i32[64]   (per-(c,e) argmax histogram)  - zeroed each call
//   512    : gate    f32[CT]
//   66048  : index   i32[CT]

// ---------------------------------------------------------------------------
// Router phase, butterfly edition (R6-verified math): 16 tokens/block, 4/wave.
// Butterfly transpose-reduce (63 shuffles vs 384) leaves lane l the complete
// logit for (tk=l>>4, e=l&15); softmax/argmax/aux run wave-parallel in 16-lane
// groups; LDS accumulation is 64 parallel bank-conflict-free atomics.
// ---------------------------------------------------------------------------
__device__ __forceinline__ void do_router(
    const float* __restrict__ in, const float* __restrict__ w,
    const float* __restrict__ noise, float* __restrict__ gate,
    int* __restrict__ index, float* __restrict__ auxpart,
    int* __restrict__ counts, float* psum, int* hcnt)
{
    const int tid = threadIdx.x;
    if (tid < E_DIM) { psum[tid] = 0.0f; hcnt[tid] = 0; }
    __syncthreads();

    const int wave = tid >> 6;
    const int lane = tid & 63;
    const int g0   = blockIdx.x * 16 + wave * 4;   // 4 tokens per wave

    float val[64];
    #pragma unroll
    for (int i = 0; i < 64; ++i) val[i] = 0.0f;

    #pragma unroll
    for (int r = 0; r < 4; ++r) {
        const int d0 = r * 256 + lane * 4;
        float4 x[4];
        #pragma unroll
        for (int tk = 0; tk < 4; ++tk) {
            const float4 a = *(const float4*)(in    + (size_t)(g0 + tk) * D_DIM + d0);
            const float4 n = *(const float4*)(noise + (size_t)(g0 + tk) * D_DIM + d0);
            x[tk] = make_float4(a.x * n.x, a.y * n.y, a.z * n.z, a.w * n.w);
        }
        #pragma unroll
        for (int e = 0; e < 16; ++e) {
            const float4 wv = *(const float4*)(w + e * D_DIM + d0);
            #pragma unroll
            for (int tk = 0; tk < 4; ++tk) {
                val[bitrev6(tk * 16 + e)] += x[tk].x * wv.x + x[tk].y * wv.y
                                           + x[tk].z * wv.z + x[tk].w * wv.w;
            }
        }
    }

    // Butterfly transpose-reduce: 63 shuffles; lane l ends with the full dot
    // for flattened idx l (bitrev6 flatten compensates the halving order).
    #pragma unroll
    for (int m = 0; m < 6; ++m) {
        const int half = 32 >> m;
        const int bit  = (lane >> m) & 1;
        #pragma unroll
        for (int j = 0; j < half; ++j) {
            const float send = bit ? val[j] : val[j + half];
            const float recv = __shfl_xor(send, 1 << m, 64);
            val[j] = (bit ? val[j + half] : val[j]) + recv;
        }
    }

    const int tk = lane >> 4;
    const int e  = lane & 15;
    const float logit = val[0];
    const int g = g0 + tk;

    // 16-lane-group max with first-index tie-break
    float mv = logit; int am = e;
    #pragma unroll
    for (int msk = 1; msk <= 8; msk <<= 1) {
        const float ov = __shfl_xor(mv, msk, 64);
        const int   oe = __shfl_xor(am, msk, 64);
        if (ov > mv || (ov == mv && oe < am)) { mv = ov; am = oe; }
    }

    const float p = __expf(logit - mv);
    float s = p;
    #pragma unroll
    for (int msk = 1; msk <= 8; msk <<= 1)
        s += __shfl_xor(s, msk, 64);

    const float inv = 1.0f / s;
    if (e == am) {                       // exactly one lane per token
        gate[g]  = inv;                  // probs[argmax] = exp(0)/s
        index[g] = am;
        atomicAdd(&hcnt[am], 1);
    }

    // per-e total of normalized probs over this wave's 4 tokens:
    // xor-16/32 sums across tk groups; afterwards all lanes hold the per-e
    // wave total, lanes 0..15 add it once (16 banks, conflict-free).
    float pn = p * inv;
    pn += __shfl_xor(pn, 16, 64);
    pn += __shfl_xor(pn, 32, 64);
    if (lane < 16)
        atomicAdd(&psum[e], pn);

    __syncthreads();
    if (tid < 16) {
        const int c = blockIdx.x >> 8;   // 256 blocks per c
        atomicAdd(&auxpart[c * 16 + tid], psum[tid]);
        atomicAdd(&counts [c * 16 + tid], hcnt[tid]);
    }
}

__device__ __forceinline__ void do_fill(float4* __restrict__ out4)
{
    const float4 z = make_float4(0.f, 0.f, 0.f, 0.f);
    float4* dst = out4 + (size_t)blockIdx.x * F4_PER_BLOCK;
    #pragma unroll 4
    for (int i = threadIdx.x; i < F4_PER_BLOCK; i += 256)
        dst[i] = z;
}

// ---------------------------------------------------------------------------
// Fused kernel with PARITY STAGGER (R7): even blocks route then fill, odd
// blocks fill then route — half the resident waves stream writes while the
// other half streams reads.
// ---------------------------------------------------------------------------
__global__ __launch_bounds__(256) void fused_router_fill_kernel(
    const float* __restrict__ in, const float* __restrict__ w,
    const float* __restrict__ noise, float* __restrict__ gate,
    int* __restrict__ index, float* __restrict__ auxpart,
    int* __restrict__ counts, float4* __restrict__ out4)
{
    __shared__ float psum[E_DIM];
    __shared__ int   hcnt[E_DIM];

    if (blockIdx.x & 1) {
        do_fill(out4);
        do_router(in, w, noise, gate, index, auxpart, counts, psum, hcnt);
    } else {
        do_router(in, w, noise, gate, index, auxpart, counts, psum, hcnt);
        do_fill(out4);
    }
}

// ---------------------------------------------------------------------------
// Finalize: <=64 nonzeros (torch scatter semantics: only tokens tp<16, e=0
// slice). Rank within expert 0 computed from the first 16 indices (<=16<CAP).
// ---------------------------------------------------------------------------
__global__ __launch_bounds__(64) void finalize_kernel(
    const float* __restrict__ gate, const int* __restrict__ index,
    const int* __restrict__ counts, const float* __restrict__ auxpart,
    float* __restrict__ out)
{
    const int id = threadIdx.x;          // 0..63
    const int c  = id >> 4;
    const int tp = id & 15;
    const int cnt = counts[id];

    float term = ((float)cnt * (1.0f / T_DIM)) * (auxpart[id] * (1.0f / T_DIM));

    if (cnt > 0) {                        // expert value tp appears as an argmax
        const int g     = c * T_DIM + tp;
        const int myidx = index[g];
        int s = 0;
        if (myidx == 0) {                 // 1-based rank within expert 0 among tokens 0..tp
            int r = 0;
            for (int t = 0; t <= tp; ++t)
                r += (index[c * T_DIM + t] == 0);
            s = r;
        }
        const size_t off = ((size_t)g * E_DIM + 0) * CAP + (size_t)s;
        out[off]            = 1.0f;       // dispatch
        out[OUT_ONE + off]  = gate[g];    // combine
    }

    #pragma unroll
    for (int off = 32; off; off >>= 1)
        term += __shfl_down(term, off, 64);
    if (id == 0)
        out[2 * OUT_ONE] = 16.0f * term;  // aux_loss = E * sum(density1*proxy)
}

extern "C" void kernel_launch(void* const* d_in, const int* in_sizes, int n_in,
                              void* d_out, int out_size, void* d_ws, size_t ws_size,
                              hipStream_t stream) {
    const float* in    = (const float*)d_in[0];
    const float* w     = (const float*)d_in[1];
    const float* noise = (const float*)d_in[2];
    float* out = (float*)d_out;

    char* ws = (char*)d_ws;
    float* auxpart = (float*)(ws);
    int*   counts  = (int*)(ws + 256);
    float* gate    = (float*)(ws + 512);
    int*   index   = (int*)(ws + 512 + 65536);

    (void)hipMemsetAsync(ws, 0, 512, stream);

    fused_router_fill_kernel<<<dim3(NBLOCKS), dim3(256), 0, stream>>>(
        in, w, noise, gate, index, auxpart, counts, (float4*)out);
    finalize_kernel<<<dim3(1), dim3(64), 0, stream>>>(gate, index, counts, auxpart, out);
}